// Round 7
// baseline (266.401 us; speedup 1.0000x reference)
//
#include <hip/hip_runtime.h>

typedef float v4 __attribute__((ext_vector_type(4)));

#define D_MODEL 1024
#define D_STATE 64
#define CHUNK   256
#define TILE_T  64

// Grid: 512 blocks = 64 bc-chunks x 8 d-slices (128 d each). Block 512 thr =
// 8 waves -> 2 blocks/CU (128 KB LDS), 16 waves/CU, 4 waves/SIMD.
// R2/R5/R6 showed: LDS instrs dropped 160->32/CU/t with time flat at ~1250
// cyc/t and VALUBusy ~50% -> bottleneck is dependency-stall exposure at only
// 2 waves/SIMD, not any pipe. This round doubles TLP (4 waves/SIMD, R2's
// level) while keeping R6's low LDS pressure (d_t=4, 2 ds_read_b128/thr/t):
// thread owns 4 n x 4 d (ng = tid&15 -> n in [ng*4,ng*4+4); dp = tid>>4).
// Reduction over 16 n-groups entirely on VALU: quad_perm xor1+xor2, then
// row_shl:4 and row_shl:8 accumulate the 4 quads of each 16-lane row into
// lane ng==0 (bound_ctrl=0 zero-fill is benign for adds).
template <int CTRL>
__device__ __forceinline__ float dpp_add(float v) {
    int p = __builtin_amdgcn_update_dpp(
        0, __builtin_bit_cast(int, v), CTRL, 0xF, 0xF, true);
    return v + __builtin_bit_cast(float, p);
}

__global__ __launch_bounds__(512, 4)
void YvParallelScan_kernel(const float* __restrict__ u,
                           const float* __restrict__ B,
                           const float* __restrict__ C,
                           const float* __restrict__ A_log,
                           float* __restrict__ out) {
    __shared__ v4 sB[2][TILE_T * 16];   // [buf][tl][n/4]  16 KB each
    __shared__ v4 sC[2][TILE_T * 16];

    const int bid = blockIdx.x;
    const int bc  = bid >> 3;          // 0..63  (batch*chunk index)
    const int dsl = bid & 7;           // d-slice (128 d each)
    const int tid = threadIdx.x;
    const int ng  = tid & 15;          // n-group of 16 (thread owns 4 n)
    const int dp  = tid >> 4;          // 0..31: d-quad within slice
    const int d   = dsl * 128 + dp * 4;
    const int rowbase = bc * CHUNK;

    v4 a4[4], h4[4];
#pragma unroll
    for (int j = 0; j < 4; ++j) {
        const int n = ng * 4 + j;
        v4 al = *(const v4*)(A_log + (size_t)n * D_MODEL + d);
        v4 na;
        na[0] = -__expf(al[0]); na[1] = -__expf(al[1]);
        na[2] = -__expf(al[2]); na[3] = -__expf(al[3]);
        a4[j] = na;
        v4 z = {0.f, 0.f, 0.f, 0.f};
        h4[j] = z;
    }

    const v4* Bg = (const v4*)(B + (size_t)rowbase * D_STATE);
    const v4* Cg = (const v4*)(C + (size_t)rowbase * D_STATE);
    const float* uptr = u   + (size_t)rowbase * D_MODEL + d;
    float*       optr = out + (size_t)rowbase * D_MODEL + d;

    // prologue: stage tile 0 into buf 0 (2 v4 per thread per array)
    v4 rb[2], rc[2];
#pragma unroll
    for (int k = 0; k < 2; ++k) {
        rb[k] = Bg[k * 512 + tid];
        rc[k] = Cg[k * 512 + tid];
    }
#pragma unroll
    for (int k = 0; k < 2; ++k) {
        sB[0][k * 512 + tid] = rb[k];
        sC[0][k * 512 + tid] = rc[k];
    }

    // x prefetch depth 2
    v4 x0 = *(const v4*)(uptr);
    v4 x1 = *(const v4*)(uptr + D_MODEL);

    __syncthreads();

    for (int ti = 0; ti < CHUNK / TILE_T; ++ti) {
        const int cur = ti & 1;

        // issue next tile's global loads early (stall at most once per 64 t)
        if (ti < CHUNK / TILE_T - 1) {
#pragma unroll
            for (int k = 0; k < 2; ++k) {
                rb[k] = Bg[(ti + 1) * 1024 + k * 512 + tid];
                rc[k] = Cg[(ti + 1) * 1024 + k * 512 + tid];
            }
        }

#pragma unroll 4
        for (int tl = 0; tl < TILE_T; ++tl) {
            const int t  = ti * TILE_T + tl;
            const int tp = (t + 2 < CHUNK) ? t + 2 : CHUNK - 1;
            const v4 xn = *(const v4*)(uptr + (size_t)tp * D_MODEL);

            // 2 broadcast ds_read_b128: this thread's 4-n slice of B and C
            const v4 b = sB[cur][tl * 16 + ng];
            const v4 c = sC[cur][tl * 16 + ng];

            v4 acc = {0.f, 0.f, 0.f, 0.f};
#pragma unroll
            for (int j = 0; j < 4; ++j) {
                h4[j] = a4[j] * h4[j] + b[j] * x0;
                acc  += c[j] * h4[j];
            }

            // 16-lane n-reduction on the VALU pipe (per v4 component)
#pragma unroll
            for (int kcomp = 0; kcomp < 4; ++kcomp) {
                float s = acc[kcomp];
                s = dpp_add<0xB1>(s);    // quad_perm [1,0,3,2]  (xor 1)
                s = dpp_add<0x4E>(s);    // quad_perm [2,3,0,1]  (xor 2)
                s = dpp_add<0x104>(s);   // row_shl:4 (+ quad 1)
                s = dpp_add<0x108>(s);   // row_shl:8 (+ quads 2,3)
                acc[kcomp] = s;
            }
            if (ng == 0) {
                *(v4*)(optr + (size_t)t * D_MODEL) = acc;  // dwordx4
            }
            x0 = x1; x1 = xn;
        }

        // write next tile into the other buffer; single barrier per tile
        if (ti < CHUNK / TILE_T - 1) {
#pragma unroll
            for (int k = 0; k < 2; ++k) {
                sB[cur ^ 1][k * 512 + tid] = rb[k];
                sC[cur ^ 1][k * 512 + tid] = rc[k];
            }
        }
        __syncthreads();
    }
}

extern "C" void kernel_launch(void* const* d_in, const int* in_sizes, int n_in,
                              void* d_out, int out_size, void* d_ws, size_t ws_size,
                              hipStream_t stream) {
    const float* u     = (const float*)d_in[0];
    // d_in[1] = delta, unused by the reference forward
    const float* B     = (const float*)d_in[2];
    const float* C     = (const float*)d_in[3];
    const float* A_log = (const float*)d_in[4];
    float* out = (float*)d_out;

    YvParallelScan_kernel<<<512, 512, 0, stream>>>(u, B, C, A_log, out);
}